// Round 6
// baseline (266.048 us; speedup 1.0000x reference)
//
#include <hip/hip_runtime.h>

// ============================================================================
// ESupConLoss on MI355X (gfx950) — round 6.
//
// out = ( pt_loss + sum_i[ -pos_i + neg_i + 2*dot(au_i,tp_i) ] ) / (N+2)
//   P[i]  = sum_{j!=i} e^{au_i.au_j} + e^{tp_i.tp_j}   (pos = ln P)
//   Ng[i] = sum_{j!=i} e^{au_i.tp_j}                   (neg = ln Ng)
//
// Structure = round-3's verified full-sweep LDS kernel (63.5 us best), plus:
//  * __launch_bounds__(256,4) + grid 2048 -> 4 independent blocks/CU whose
//    phases drift (R3 capped residency at ~2; barrier phase-lock starved all
//    pipes at ~31%).
//  * TRUE LDS double-buffer: GLDs for tile ct+1 are issued AFTER the barrier
//    that publishes tile ct, so the vmcnt(0)+s_barrier drain at iteration
//    ct+1 waits on loads that already had a whole compute section to land.
//    Race-free: at barrier@ct all waves finished reading buf[(ct-1)&1], which
//    is the buffer ct+1 overwrites. One barrier per ct (was two).
//  * R5's correct prep-fused dd/pt terms + last-block finale (2 launches).
//
// log2-domain trick: inputs pre-scaled by sqrt(log2 e), cast bf16 -> MFMA
// dots are log2-domain, v_exp_f32 (=2^x) needs no scaling; C2=32 shift in
// the MFMA C-init cancels in -pos+neg.
// ============================================================================

typedef float f32x4 __attribute__((ext_vector_type(4)));
typedef __bf16 bf16x8 __attribute__((ext_vector_type(8)));

static constexpr int   N_ROWS = 8192;
static constexpr int   DIM    = 128;
static constexpr float SQRT_LOG2E = 1.2011224087864498f; // sqrt(log2(e))
static constexpr float C2  = 32.0f;                      // log2-domain shift
static constexpr float LN2 = 0.6931471805599453f;

// ---------------- ws layout (bytes) ----------------
// bau    : bf16[8192*128] @ 0
// btp    : bf16[8192*128] @ 2097152
// P      : f32[8192]      @ 4194304
// Ng     : f32[8192]      @ 4227072
// dd     : f32[8192]      @ 4259840   (au_i . tp_i, f32)
// ptpart : f32[1024]      @ 4292608   (per-prep-block pt partials)
// done   : u32            @ 4296704

__device__ inline unsigned short f2bf_rne(float x) {
    unsigned u = __builtin_bit_cast(unsigned, x);
    u += 0x7fffu + ((u >> 16) & 1u);
    return (unsigned short)(u >> 16);
}

#define GLD16(gptr, lptr)                                                  \
    __builtin_amdgcn_global_load_lds(                                      \
        (const __attribute__((address_space(1))) void*)(gptr),             \
        (__attribute__((address_space(3))) void*)(lptr), 16, 0, 0)

// ---------------------------------------------------------------------------
// Kernel 1: bf16 convert + dd[i] + pt partials + zero P/Ng/done.
// (verified round 5, absmax 0)
// ---------------------------------------------------------------------------
__global__ void prep_kernel(const float* __restrict__ zau,
                            const float* __restrict__ ztp,
                            const float* __restrict__ fc,
                            unsigned short* __restrict__ bau,
                            unsigned short* __restrict__ btp,
                            float* __restrict__ P, float* __restrict__ Ng,
                            float* __restrict__ dd, float* __restrict__ ptpart,
                            unsigned* __restrict__ done) {
    __shared__ float pw[4];
    const int tid  = threadIdx.x;
    const int gid  = blockIdx.x * 256 + tid;
    const int lane = tid & 63;
    const int base = gid * 4;
    const int seg  = gid & 31;

    float4 a = *reinterpret_cast<const float4*>(zau + base);
    float4 t = *reinterpret_cast<const float4*>(ztp + base);

    ushort4 ua, ut;
    ua.x = f2bf_rne(a.x * SQRT_LOG2E); ua.y = f2bf_rne(a.y * SQRT_LOG2E);
    ua.z = f2bf_rne(a.z * SQRT_LOG2E); ua.w = f2bf_rne(a.w * SQRT_LOG2E);
    ut.x = f2bf_rne(t.x * SQRT_LOG2E); ut.y = f2bf_rne(t.y * SQRT_LOG2E);
    ut.z = f2bf_rne(t.z * SQRT_LOG2E); ut.w = f2bf_rne(t.w * SQRT_LOG2E);
    *reinterpret_cast<ushort4*>(bau + base) = ua;
    *reinterpret_cast<ushort4*>(btp + base) = ut;

    // dd[row] = au_row . tp_row  (32 threads per row)
    float d = a.x * t.x + a.y * t.y + a.z * t.z + a.w * t.w;
    d += __shfl_xor(d, 1, 64);  d += __shfl_xor(d, 2, 64);
    d += __shfl_xor(d, 4, 64);  d += __shfl_xor(d, 8, 64);
    d += __shfl_xor(d, 16, 64);
    if ((lane & 31) == 0) dd[gid >> 5] = d;

    // pt partial: (a - t) . (pt1 - pt0) on this thread's 4 dims
    float4 w0 = *reinterpret_cast<const float4*>(fc + seg * 4);
    float4 w1 = *reinterpret_cast<const float4*>(fc + DIM + seg * 4);
    float ptp = (a.x - t.x) * (w1.x - w0.x) + (a.y - t.y) * (w1.y - w0.y)
              + (a.z - t.z) * (w1.z - w0.z) + (a.w - t.w) * (w1.w - w0.w);
    for (int m = 1; m < 64; m <<= 1) ptp += __shfl_xor(ptp, m, 64);
    if (lane == 0) pw[tid >> 6] = ptp;
    __syncthreads();
    if (tid == 0) ptpart[blockIdx.x] = pw[0] + pw[1] + pw[2] + pw[3];

    if (gid < N_ROWS) { P[gid] = 0.0f; Ng[gid] = 0.0f; }
    if (gid == 0)     { done[0] = 0u; }
}

// ---------------------------------------------------------------------------
// Kernel 2. Grid 2048 = 32 col-splits (slow) x 64 row-tiles (fast).
// Block = 4 waves, wave owns 32 rows, 8 col-tiles of 32 cols, double-buffered.
// LDS frag order (verified r2-r5): frag f (1 KiB) at ushort off f*512 within
// a buffer; lane slot = lane*16B. f = arr*8 + nt*4 + k.
// MFMA 16x16x32 bf16 (HW-verified): A/B elem j of lane -> idx (lane&15),
// k=(lane>>4)*8+j; C/D reg r -> row (lane>>4)*4+r, col (lane&15).
// ---------------------------------------------------------------------------
__global__ __launch_bounds__(256, 4)
void score_kernel(const unsigned short* __restrict__ bau,
                  const unsigned short* __restrict__ btp,
                  float* __restrict__ P, float* __restrict__ Ng,
                  const float* __restrict__ dd,
                  const float* __restrict__ ptpart,
                  unsigned* __restrict__ done,
                  float* __restrict__ out) {
    __shared__ __align__(16) unsigned short lds[2][16 * 512];   // 32 KiB
    __shared__ float red[4], red2[4];
    __shared__ int lastflag;

    const int tid  = threadIdx.x;
    const int lane = tid & 63;
    const int wave = tid >> 6;
    const int quad = lane >> 4;
    const int l15  = lane & 15;
    const int rb   = blockIdx.x & 63;   // row tile (fast index)
    const int cs   = blockIdx.x >> 6;   // col split 0..31 (slow index)
    const int r0w  = rb * 128 + wave * 32;
    const int laneoff = l15 * 256 + quad * 16;  // per-lane global byte offset

    // loop-invariant A fragments (rows of au / tp), 64 VGPRs
    bf16x8 aAu[2][4], aTp[2][4];
#pragma unroll
    for (int mt = 0; mt < 2; mt++) {
        int row = r0w + mt * 16 + l15;
        const unsigned short* pa = bau + row * DIM + quad * 8;
        const unsigned short* pt = btp + row * DIM + quad * 8;
#pragma unroll
        for (int k = 0; k < 4; k++) {
            aAu[mt][k] = *reinterpret_cast<const bf16x8*>(pa + k * 32);
            aTp[mt][k] = *reinterpret_cast<const bf16x8*>(pt + k * 32);
        }
    }

    float sP[2][4] = {{0.f,0.f,0.f,0.f},{0.f,0.f,0.f,0.f}};
    float sN[2][4] = {{0.f,0.f,0.f,0.f},{0.f,0.f,0.f,0.f}};

    // wave-uniform fragment assignment for staging: f = wave*4 + j
    const int f0   = wave * 4;
    // prologue: stage tile 0 into buffer 0
    {
        const int colbase = cs * 256;
#pragma unroll
        for (int j = 0; j < 4; j++) {
            const int f   = f0 + j;
            const int arr = f >> 3;
            const int nt  = (f >> 2) & 1;
            const int k   = f & 3;
            const char* gb = (const char*)(arr ? btp : bau)
                           + ((size_t)(colbase + nt * 16) << 8) + (k << 6);
            GLD16(gb + laneoff, &lds[0][f << 9]);
        }
    }

    for (int ct = 0; ct < 8; ct++) {
        const int colbase = cs * 256 + ct * 32;
        const int cur = ct & 1;

        // single barrier: drains buf[cur] writes (vmcnt0 before s_barrier)
        // and guarantees all waves finished reading buf[cur^1] (tile ct-1).
        __syncthreads();

        // issue NEXT tile's staging into the buffer just freed (ct+1 parity)
        if (ct + 1 < 8) {
            const int ncol = colbase + 32;
#pragma unroll
            for (int j = 0; j < 4; j++) {
                const int f   = f0 + j;
                const int arr = f >> 3;
                const int nt  = (f >> 2) & 1;
                const int k   = f & 3;
                const char* gb = (const char*)(arr ? btp : bau)
                               + ((size_t)(ncol + nt * 16) << 8) + (k << 6);
                GLD16(gb + laneoff, &lds[cur ^ 1][f << 9]);
            }
        }

        const bool dg = (colbase < r0w + 32) && (colbase + 32 > r0w);

        // ---- au B-fragments, MFMA s_aa ----
        bf16x8 bA[2][4];
#pragma unroll
        for (int nt = 0; nt < 2; nt++)
#pragma unroll
            for (int k = 0; k < 4; k++)
                bA[nt][k] = *reinterpret_cast<const bf16x8*>(
                    &lds[cur][((nt * 4 + k) << 9) + lane * 8]);

        f32x4 accA[2][2];
#pragma unroll
        for (int mt = 0; mt < 2; mt++)
#pragma unroll
            for (int nt = 0; nt < 2; nt++)
                accA[mt][nt] = f32x4{-C2, -C2, -C2, -C2};
#pragma unroll
        for (int k = 0; k < 4; k++)
#pragma unroll
            for (int mt = 0; mt < 2; mt++) {
                accA[mt][0] = __builtin_amdgcn_mfma_f32_16x16x32_bf16(
                    aAu[mt][k], bA[0][k], accA[mt][0], 0, 0, 0);
                accA[mt][1] = __builtin_amdgcn_mfma_f32_16x16x32_bf16(
                    aAu[mt][k], bA[1][k], accA[mt][1], 0, 0, 0);
            }

        // ---- tp B-fragments (ds_read latency hides under exp-aa) ----
        bf16x8 bT[2][4];
#pragma unroll
        for (int nt = 0; nt < 2; nt++)
#pragma unroll
            for (int k = 0; k < 4; k++)
                bT[nt][k] = *reinterpret_cast<const bf16x8*>(
                    &lds[cur][((8 + nt * 4 + k) << 9) + lane * 8]);

        // ---- exp s_aa ----
#pragma unroll
        for (int mt = 0; mt < 2; mt++)
#pragma unroll
            for (int nt = 0; nt < 2; nt++)
#pragma unroll
                for (int r = 0; r < 4; r++) {
                    float e = __builtin_amdgcn_exp2f(accA[mt][nt][r]);
                    if (dg) {
                        int grow = r0w + mt * 16 + quad * 4 + r;
                        int gcol = colbase + nt * 16 + l15;
                        if (grow == gcol) e = 0.f;
                    }
                    sP[mt][r] += e;
                }

        // ---- MFMA s_tt and s_at (shared tp fragments) ----
        f32x4 accT[2][2], accX[2][2];
#pragma unroll
        for (int mt = 0; mt < 2; mt++)
#pragma unroll
            for (int nt = 0; nt < 2; nt++) {
                accT[mt][nt] = f32x4{-C2, -C2, -C2, -C2};
                accX[mt][nt] = f32x4{-C2, -C2, -C2, -C2};
            }
#pragma unroll
        for (int k = 0; k < 4; k++)
#pragma unroll
            for (int mt = 0; mt < 2; mt++) {
                accT[mt][0] = __builtin_amdgcn_mfma_f32_16x16x32_bf16(
                    aTp[mt][k], bT[0][k], accT[mt][0], 0, 0, 0);
                accX[mt][0] = __builtin_amdgcn_mfma_f32_16x16x32_bf16(
                    aAu[mt][k], bT[0][k], accX[mt][0], 0, 0, 0);
                accT[mt][1] = __builtin_amdgcn_mfma_f32_16x16x32_bf16(
                    aTp[mt][k], bT[1][k], accT[mt][1], 0, 0, 0);
                accX[mt][1] = __builtin_amdgcn_mfma_f32_16x16x32_bf16(
                    aAu[mt][k], bT[1][k], accX[mt][1], 0, 0, 0);
            }

        // ---- exp s_tt, s_at ----
#pragma unroll
        for (int mt = 0; mt < 2; mt++)
#pragma unroll
            for (int nt = 0; nt < 2; nt++)
#pragma unroll
                for (int r = 0; r < 4; r++) {
                    float eT = __builtin_amdgcn_exp2f(accT[mt][nt][r]);
                    float eX = __builtin_amdgcn_exp2f(accX[mt][nt][r]);
                    if (dg) {
                        int grow = r0w + mt * 16 + quad * 4 + r;
                        int gcol = colbase + nt * 16 + l15;
                        if (grow == gcol) { eT = 0.f; eX = 0.f; }
                    }
                    sP[mt][r] += eT;
                    sN[mt][r] += eX;
                }
    }

    // ---- reduce across the 16 lanes of each quad, one atomic per row ----
#pragma unroll
    for (int mt = 0; mt < 2; mt++)
#pragma unroll
        for (int r = 0; r < 4; r++) {
            float p = sP[mt][r], ng = sN[mt][r];
            p  += __shfl_xor(p, 1, 64);  p  += __shfl_xor(p, 2, 64);
            p  += __shfl_xor(p, 4, 64);  p  += __shfl_xor(p, 8, 64);
            ng += __shfl_xor(ng, 1, 64); ng += __shfl_xor(ng, 2, 64);
            ng += __shfl_xor(ng, 4, 64); ng += __shfl_xor(ng, 8, 64);
            if (l15 == 0) {
                int row = r0w + mt * 16 + quad * 4 + r;
                atomicAdd(&P[row],  p);
                atomicAdd(&Ng[row], ng);
            }
        }

    // ---------------- finale: last block reduces the scalar ----------------
    __syncthreads();
    if (tid == 0) {
        __threadfence();
        unsigned t = atomicAdd(done, 1u);
        lastflag = (t == (unsigned)(gridDim.x - 1)) ? 1 : 0;
    }
    __syncthreads();
    if (lastflag) {
        __threadfence();   // acquire
        float ssum = 0.f, psum = 0.f;
        for (int i = tid; i < N_ROWS; i += 256) {
            float p  = __hip_atomic_load(&P[i],  __ATOMIC_RELAXED,
                                         __HIP_MEMORY_SCOPE_AGENT);
            float ng = __hip_atomic_load(&Ng[i], __ATOMIC_RELAXED,
                                         __HIP_MEMORY_SCOPE_AGENT);
            ssum += LN2 * (__builtin_amdgcn_logf(ng) -
                           __builtin_amdgcn_logf(p)) + 2.0f * dd[i];
        }
        for (int i = tid; i < 1024; i += 256) psum += ptpart[i];
        for (int m = 1; m < 64; m <<= 1) {
            ssum += __shfl_xor(ssum, m, 64);
            psum += __shfl_xor(psum, m, 64);
        }
        if (lane == 0) { red[wave] = ssum; red2[wave] = psum; }
        __syncthreads();
        if (tid == 0) {
            float S  = red[0] + red[1] + red[2] + red[3];
            float Pt = red2[0] + red2[1] + red2[2] + red2[3];
            out[0] = (Pt / (float)N_ROWS + S) / (float)(N_ROWS + 2);
        }
    }
}

extern "C" void kernel_launch(void* const* d_in, const int* in_sizes, int n_in,
                              void* d_out, int out_size, void* d_ws, size_t ws_size,
                              hipStream_t stream) {
    const float* zau = (const float*)d_in[0];
    const float* ztp = (const float*)d_in[1];
    const float* fc  = (const float*)d_in[2];
    // d_in[3] = labels (unused by the math)
    float* out = (float*)d_out;

    char* ws = (char*)d_ws;
    unsigned short* bau = (unsigned short*)(ws);
    unsigned short* btp = (unsigned short*)(ws + 2097152);
    float*    P      = (float*)(ws + 4194304);
    float*    Ng     = (float*)(ws + 4227072);
    float*    dd     = (float*)(ws + 4259840);
    float*    ptpart = (float*)(ws + 4292608);
    unsigned* done   = (unsigned*)(ws + 4296704);

    prep_kernel<<<dim3(1024), dim3(256), 0, stream>>>(
        zau, ztp, fc, bau, btp, P, Ng, dd, ptpart, done);
    score_kernel<<<dim3(2048), dim3(256), 0, stream>>>(
        bau, btp, P, Ng, dd, ptpart, done, out);
}